// Round 6
// baseline (667.040 us; speedup 1.0000x reference)
//
#include <hip/hip_runtime.h>
#include <hip/hip_bf16.h>
#include <hip/hip_cooperative_groups.h>

namespace cg = cooperative_groups;

// Cabasc: B=64, S=512, Ta=8, D=768
// Round 6: cooperative mega-kernel, grid-stride phases, occupancy-sized grid,
// return-code-checked launch with multi-kernel fallback (round-4 pipeline).

#define NB 64
#define NS 512
#define ND 768
#define NTA 8

typedef __attribute__((ext_vector_type(8))) __bf16 bf16x8;
typedef __attribute__((ext_vector_type(4))) float f32x4;

// ---- workspace layout (bytes) ----
#define OFF_SCORES 0u           // NB*NS f32   = 131072
#define OFF_VS 131072u          // NB*ND f32
#define OFF_VTS 327680u         // NB*ND f32
#define OFF_CTX 524288u         // NB*ND f32
#define OFF_U 720896u           // NB*ND f32
#define ZERO_BYTES 917504u      // zeroed in P0
#define OFF_VA 917504u          // NB*ND f32
#define OFF_LENS 1245184u       // mlenf[64] | inv_mlen[64] | inv_alen[64]
#define OFF_W1MT 1246208u       // ND*ND bf16
#define OFF_MP 2425856u         // NB*NS*ND bf16

__device__ __forceinline__ float fast_tanh(float x) {
  x = fminf(fmaxf(x, -15.f), 15.f);
  float t = __expf(2.f * x);
  return __fdividef(t - 1.f, t + 1.f);
}

__device__ __forceinline__ unsigned bfpack2(float a, float b) {
  unsigned ua = __float_as_uint(a), ub = __float_as_uint(b);
  ua = (ua + 0x7FFFu + ((ua >> 16) & 1u)) >> 16;
  ub = (ub + 0x7FFFu + ((ub >> 16) & 1u)) >> 16;
  return ua | (ub << 16);
}

__device__ __forceinline__ unsigned short bf16b(float f) {
  unsigned u = __float_as_uint(f);
  u = (u + 0x7FFFu + ((u >> 16) & 1u)) >> 16;
  return (unsigned short)u;
}

__device__ __forceinline__ void async_copy16(const void* g, void* l) {
  __builtin_amdgcn_global_load_lds(
      (const __attribute__((address_space(1))) void*)g,
      (__attribute__((address_space(3))) void*)l, 16, 0, 0);
}

// ======================= cooperative mega-kernel ===========================
__global__ __launch_bounds__(256, 4) void k_mega(
    const float* __restrict__ memory, const float* __restrict__ aspect,
    const int* __restrict__ ids, const int* __restrict__ tids,
    const float* __restrict__ W1, const float* __restrict__ b1,
    const float* __restrict__ w2, const float* __restrict__ Wm,
    const float* __restrict__ bm, const float* __restrict__ Wd,
    const float* __restrict__ bd, float* __restrict__ out,
    float* __restrict__ scores, float* __restrict__ v_s,
    float* __restrict__ v_ts, float* __restrict__ ctx, float* __restrict__ u,
    float* __restrict__ v_a, float* __restrict__ lens,
    unsigned short* __restrict__ w1mt, unsigned short* __restrict__ mp,
    char* __restrict__ zws) {
  cg::grid_group grid = cg::this_grid();
  const int bid = blockIdx.x, tid = threadIdx.x;
  const int nblk = gridDim.x;
  __shared__ __align__(16) char smem[32768];

  // ---- P0: transpose W1_m -> bf16 [e][d] / lens + v_a / zero accumulators --
  for (int vb = bid; vb < 864; vb += nblk) {
    if (vb < 576) {
      float(*tile)[33] = (float(*)[33])smem;
      int bx = vb % 24, by = vb / 24;
      int tx = tid & 31, ty = tid >> 5;
      for (int j = 0; j < 32; j += 8)
        tile[ty + j][tx] = W1[(size_t)(by * 32 + ty + j) * ND + bx * 32 + tx];
      __syncthreads();
      for (int j = 0; j < 32; j += 8)
        w1mt[(size_t)(bx * 32 + ty + j) * ND + by * 32 + tx] = bf16b(tile[tx][ty + j]);
    } else if (vb < 640) {
      int b = vb - 576;
      int* red = (int*)smem;
      float* sh_inva = (float*)(smem + 1024);
      int cnt = 0;
      for (int j = tid; j < NS; j += 256) cnt += (ids[b * NS + j] != 0);
      red[tid] = cnt;
      __syncthreads();
      for (int s = 128; s > 0; s >>= 1) {
        if (tid < s) red[tid] += red[tid + s];
        __syncthreads();
      }
      if (tid == 0) {
        int mlen = red[0];
        int acnt = 0;
        for (int t = 0; t < NTA; ++t) acnt += (tids[b * NTA + t] != 0);
        lens[b] = (float)mlen;
        lens[64 + b] = 1.0f / (float)mlen;
        float inva = 1.0f / (float)acnt;
        lens[128 + b] = inva;
        *sh_inva = inva;
      }
      __syncthreads();
      float inva = *sh_inva;
      for (int j = tid; j < ND; j += 256) {
        float s = 0.f;
        for (int t = 0; t < NTA; ++t) s += aspect[((size_t)b * NTA + t) * ND + j];
        v_a[b * ND + j] = s * inva;
      }
    } else {
      uint4 z = {0u, 0u, 0u, 0u};
      *(uint4*)(zws + (size_t)(vb - 640) * 4096 + tid * 16) = z;
    }
    __syncthreads();  // WAR guard before smem reuse next iteration
  }
  grid.sync();

  // ---- P1: v_s (mean of memory) + mp = bf16(memory*loc) --------------------
  for (int vb = bid; vb < 1024; vb += nblk) {
    int b = vb >> 4, sc = vb & 15;
    if (tid < 192) {
      int d0 = tid * 4;
      float inv_mlen = lens[64 + b];
      float mlenf = lens[b];
      float s0 = 0, s1 = 0, s2 = 0, s3 = 0;
      for (int s = 0; s < 32; ++s) {
        int srow = sc * 32 + s;
        size_t row = (size_t)b * NS + srow;
        const float4 v = *(const float4*)(memory + row * ND + d0);
        s0 += v.x; s1 += v.y; s2 += v.z; s3 += v.w;
        float fs = (float)srow;
        float loc = (fs < mlenf) ? 1.0f - fs * inv_mlen : 1.0f;
        uint2 pk;
        pk.x = bfpack2(v.x * loc, v.y * loc);
        pk.y = bfpack2(v.z * loc, v.w * loc);
        *(uint2*)(mp + row * ND + d0) = pk;
      }
      float* p = v_s + b * ND + d0;
      atomicAdd(p + 0, s0 * inv_mlen);
      atomicAdd(p + 1, s1 * inv_mlen);
      atomicAdd(p + 2, s2 * inv_mlen);
      atomicAdd(p + 3, s3 * inv_mlen);
    }
  }
  grid.sync();

  // ---- P2: ctx += partial([v_a;v_s] @ [W1_a;W1_s]) -------------------------
  for (int vb = bid; vb < 768; vb += nblk) {
    int et = vb >> 8, r = vb & 255;
    int b = r >> 2, dc = r & 3;
    float* vbuf = (float*)smem;  // 384 f32
    for (int j = tid; j < 384; j += 256) {
      int k = dc * 384 + j;
      vbuf[j] = (k < ND) ? v_a[b * ND + k] : v_s[b * ND + (k - ND)];
    }
    __syncthreads();
    int e = et * 256 + tid;
    float acc = 0.f;
    const float* Wk = W1 + (size_t)(ND + dc * 384) * ND + e;
#pragma unroll 8
    for (int j = 0; j < 384; ++j) acc += vbuf[j] * Wk[(size_t)j * ND];
    atomicAdd(&ctx[b * ND + e], acc);
    __syncthreads();
  }
  grid.sync();

  // ---- P3: big GEMM, persistent over 1536 tiles ----------------------------
  {
    char* ldsA = smem;
    char* ldsB = smem + 16384;
    const int wave = tid >> 6, lane = tid & 63;
    const int wm = wave & 1, wn = wave >> 1;
    const int lrow = lane >> 3;
    const int qlog = (lane & 7) ^ lrow;
    const int q2 = lane >> 4, c = lane & 15;

    for (int t = bid; t < 1536; t += nblk) {
      const int xcd = t & 7, jj = t >> 3;
      const int et = jj % 6;
      const int rt = xcd * 32 + jj / 6;
      const int row0 = rt * 128, n0 = et * 128;
      const int b = row0 >> 9;

      const char* Abase = (const char*)mp + (size_t)(row0 + lrow) * (ND * 2) + qlog * 16;
      const char* Bbase = (const char*)w1mt + (size_t)(n0 + lrow) * (ND * 2) + qlog * 16;

      f32x4 acc[4][4];
#pragma unroll
      for (int i = 0; i < 4; ++i)
#pragma unroll
        for (int t2 = 0; t2 < 4; ++t2) acc[i][t2] = (f32x4){0.f, 0.f, 0.f, 0.f};

      int offA0[4], offB0[4];
#pragma unroll
      for (int i = 0; i < 4; ++i) {
        int ml = wm * 64 + i * 16 + c;
        offA0[i] = ml * 128 + ((q2 ^ (ml & 7)) * 16);
        int nl = wn * 64 + i * 16 + c;
        offB0[i] = nl * 128 + ((q2 ^ (nl & 7)) * 16);
      }

      __syncthreads();
      for (int kb = 0; kb < ND * 2; kb += 128) {
#pragma unroll
        for (int i = 0; i < 4; ++i) {
          int g = wave * 4 + i;
          async_copy16(Abase + (size_t)g * 8 * (ND * 2) + kb, ldsA + g * 1024);
          async_copy16(Bbase + (size_t)g * 8 * (ND * 2) + kb, ldsB + g * 1024);
        }
        __syncthreads();
#pragma unroll
        for (int kk = 0; kk < 2; ++kk) {
          const int x = kk * 64;
          bf16x8 bfrag[4];
#pragma unroll
          for (int t2 = 0; t2 < 4; ++t2) bfrag[t2] = *(const bf16x8*)(ldsB + (offB0[t2] ^ x));
#pragma unroll
          for (int i = 0; i < 4; ++i) {
            bf16x8 afrag = *(const bf16x8*)(ldsA + (offA0[i] ^ x));
#pragma unroll
            for (int t2 = 0; t2 < 4; ++t2)
              acc[i][t2] = __builtin_amdgcn_mfma_f32_16x16x32_bf16(afrag, bfrag[t2], acc[i][t2], 0, 0, 0);
          }
        }
        __syncthreads();
      }

      float ctxv[4], w2v[4];
#pragma unroll
      for (int t2 = 0; t2 < 4; ++t2) {
        int n = n0 + wn * 64 + t2 * 16 + c;
        ctxv[t2] = ctx[b * ND + n] + b1[n];
        w2v[t2] = w2[n];
      }
#pragma unroll
      for (int i = 0; i < 4; ++i) {
#pragma unroll
        for (int r = 0; r < 4; ++r) {
          float s = 0.f;
#pragma unroll
          for (int t2 = 0; t2 < 4; ++t2) s += fast_tanh(acc[i][t2][r] + ctxv[t2]) * w2v[t2];
          s += __shfl_xor(s, 1, 64);
          s += __shfl_xor(s, 2, 64);
          s += __shfl_xor(s, 4, 64);
          s += __shfl_xor(s, 8, 64);
          if (c == 0) atomicAdd(&scores[row0 + wm * 64 + i * 16 + q2 * 4 + r], s);
        }
      }
    }
  }
  grid.sync();

  // ---- P4: softmax + v_ts --------------------------------------------------
  for (int vb = bid; vb < 1024; vb += nblk) {
    int b = vb >> 4, sc = vb & 15;
    int wid = tid >> 6, lane = tid & 63;
    float* sm = (float*)smem;   // 4
    float* ssum = sm + 4;       // 4
    float* al = sm + 8;         // 32
    float v0 = scores[b * NS + tid];
    float v1 = scores[b * NS + 256 + tid];
    float m = fmaxf(v0, v1);
    for (int off = 1; off < 64; off <<= 1) m = fmaxf(m, __shfl_xor(m, off, 64));
    if (lane == 0) sm[wid] = m;
    __syncthreads();
    float M = fmaxf(fmaxf(sm[0], sm[1]), fmaxf(sm[2], sm[3]));
    float e = __expf(v0 - M) + __expf(v1 - M);
    for (int off = 1; off < 64; off <<= 1) e += __shfl_xor(e, off, 64);
    if (lane == 0) ssum[wid] = e;
    __syncthreads();
    float invS = 1.0f / (ssum[0] + ssum[1] + ssum[2] + ssum[3]);
    if (tid < 32) al[tid] = __expf(scores[b * NS + sc * 32 + tid] - M) * invS;
    __syncthreads();

    if (tid < 192) {
      int d0 = tid * 4;
      float a0 = 0, a1 = 0, a2 = 0, a3 = 0;
      for (int s = 0; s < 32; ++s) {
        size_t row = (size_t)b * NS + sc * 32 + s;
        uint2 pk = *(const uint2*)(mp + row * ND + d0);
        float a = al[s];
        a0 += a * __uint_as_float(pk.x << 16);
        a1 += a * __uint_as_float(pk.x & 0xFFFF0000u);
        a2 += a * __uint_as_float(pk.y << 16);
        a3 += a * __uint_as_float(pk.y & 0xFFFF0000u);
      }
      float* p = v_ts + b * ND + d0;
      atomicAdd(p + 0, a0);
      atomicAdd(p + 1, a1);
      atomicAdd(p + 2, a2);
      atomicAdd(p + 3, a3);
    }
    __syncthreads();
  }
  grid.sync();

  // ---- P5: u += partial((v_ts+v_s) @ Wm) -----------------------------------
  for (int vb = bid; vb < 768; vb += nblk) {
    int et = vb >> 8, r = vb & 255;
    int b = r >> 2, dc = r & 3;
    float* vbuf = (float*)smem;  // 192 f32
    for (int j = tid; j < 192; j += 256) {
      int d = dc * 192 + j;
      vbuf[j] = v_ts[b * ND + d] + v_s[b * ND + d];
    }
    __syncthreads();
    int e = et * 256 + tid;
    float acc = 0.f;
    const float* Wk = Wm + (size_t)(dc * 192) * ND + e;
#pragma unroll 8
    for (int j = 0; j < 192; ++j) acc += vbuf[j] * Wk[(size_t)j * ND];
    atomicAdd(&u[b * ND + e], acc);
    __syncthreads();
  }
  grid.sync();

  // ---- P6: logits = tanh(u+bm) @ Wd + bd -----------------------------------
  for (int vb = bid; vb < NB; vb += nblk) {
    int b = vb;
    int wid = tid >> 6, lane = tid & 63;
    float* red = (float*)smem;  // [4][3]
    float p0 = 0, p1 = 0, p2 = 0;
    for (int e = tid; e < ND; e += 256) {
      float vm = fast_tanh(u[b * ND + e] + bm[e]);
      p0 += vm * Wd[e * 3 + 0];
      p1 += vm * Wd[e * 3 + 1];
      p2 += vm * Wd[e * 3 + 2];
    }
    for (int off = 1; off < 64; off <<= 1) {
      p0 += __shfl_xor(p0, off, 64);
      p1 += __shfl_xor(p1, off, 64);
      p2 += __shfl_xor(p2, off, 64);
    }
    if (lane == 0) { red[wid * 3 + 0] = p0; red[wid * 3 + 1] = p1; red[wid * 3 + 2] = p2; }
    __syncthreads();
    if (tid == 0) {
      out[b * 3 + 0] = red[0] + red[3] + red[6] + red[9] + bd[0];
      out[b * 3 + 1] = red[1] + red[4] + red[7] + red[10] + bd[1];
      out[b * 3 + 2] = red[2] + red[5] + red[8] + red[11] + bd[2];
    }
    __syncthreads();
  }
}

// ======================= fallback kernels (round-4, verified) ===============
__global__ __launch_bounds__(256) void k_pre(const float* __restrict__ W1,
                                             unsigned short* __restrict__ w1mt,
                                             const int* __restrict__ ids,
                                             const int* __restrict__ tids,
                                             const float* __restrict__ aspect,
                                             float* __restrict__ v_a,
                                             float* __restrict__ lens,
                                             char* __restrict__ zws) {
  int bid = blockIdx.x, tid = threadIdx.x;
  if (bid < 576) {
    __shared__ float tile[32][33];
    int bx = bid % 24, by = bid / 24;
    int tx = tid & 31, ty = tid >> 5;
    for (int j = 0; j < 32; j += 8)
      tile[ty + j][tx] = W1[(size_t)(by * 32 + ty + j) * ND + bx * 32 + tx];
    __syncthreads();
    for (int j = 0; j < 32; j += 8)
      w1mt[(size_t)(bx * 32 + ty + j) * ND + by * 32 + tx] = bf16b(tile[tx][ty + j]);
  } else if (bid < 640) {
    int b = bid - 576;
    __shared__ int red[256];
    __shared__ float sh_inva;
    int cnt = 0;
    for (int j = tid; j < NS; j += 256) cnt += (ids[b * NS + j] != 0);
    red[tid] = cnt;
    __syncthreads();
    for (int s = 128; s > 0; s >>= 1) {
      if (tid < s) red[tid] += red[tid + s];
      __syncthreads();
    }
    if (tid == 0) {
      int mlen = red[0];
      int acnt = 0;
      for (int t = 0; t < NTA; ++t) acnt += (tids[b * NTA + t] != 0);
      lens[b] = (float)mlen;
      lens[64 + b] = 1.0f / (float)mlen;
      float inva = 1.0f / (float)acnt;
      lens[128 + b] = inva;
      sh_inva = inva;
    }
    __syncthreads();
    float inva = sh_inva;
    for (int j = tid; j < ND; j += 256) {
      float s = 0.f;
      for (int t = 0; t < NTA; ++t) s += aspect[((size_t)b * NTA + t) * ND + j];
      v_a[b * ND + j] = s * inva;
    }
  } else {
    uint4 z = {0u, 0u, 0u, 0u};
    *(uint4*)(zws + (size_t)(bid - 640) * 4096 + tid * 16) = z;
  }
}

__global__ __launch_bounds__(192) void k_vs_mprime(const float* __restrict__ memory,
                                                   const float* __restrict__ lens,
                                                   float* __restrict__ v_s,
                                                   unsigned short* __restrict__ mp) {
  int sc = blockIdx.x, b = blockIdx.y, tid = threadIdx.x;
  int d0 = tid * 4;
  float inv_mlen = lens[64 + b];
  float mlenf = lens[b];
  float s0 = 0, s1 = 0, s2 = 0, s3 = 0;
  for (int s = 0; s < 32; ++s) {
    int srow = sc * 32 + s;
    size_t row = (size_t)b * NS + srow;
    const float4 v = *(const float4*)(memory + row * ND + d0);
    s0 += v.x; s1 += v.y; s2 += v.z; s3 += v.w;
    float fs = (float)srow;
    float loc = (fs < mlenf) ? 1.0f - fs * inv_mlen : 1.0f;
    uint2 pk;
    pk.x = bfpack2(v.x * loc, v.y * loc);
    pk.y = bfpack2(v.z * loc, v.w * loc);
    *(uint2*)(mp + row * ND + d0) = pk;
  }
  float* p = v_s + b * ND + d0;
  atomicAdd(p + 0, s0 * inv_mlen);
  atomicAdd(p + 1, s1 * inv_mlen);
  atomicAdd(p + 2, s2 * inv_mlen);
  atomicAdd(p + 3, s3 * inv_mlen);
}

__global__ __launch_bounds__(256) void k_ctx(const float* __restrict__ W1,
                                             const float* __restrict__ v_a,
                                             const float* __restrict__ v_s,
                                             float* __restrict__ ctx) {
  int et = blockIdx.x, bt = blockIdx.y, dc = blockIdx.z, tid = threadIdx.x;
  __shared__ float vbuf[8][192];
  int b0 = bt * 8;
  for (int l = tid; l < 8 * 192; l += 256) {
    int bb = l / 192, jj = l % 192;
    int k = dc * 192 + jj;
    vbuf[bb][jj] = (k < ND) ? v_a[(b0 + bb) * ND + k] : v_s[(b0 + bb) * ND + (k - ND)];
  }
  __syncthreads();
  int e = et * 256 + tid;
  const float* Wk = W1 + (size_t)(ND + dc * 192) * ND + e;
  float acc[8] = {0.f, 0.f, 0.f, 0.f, 0.f, 0.f, 0.f, 0.f};
#pragma unroll 4
  for (int j = 0; j < 192; ++j) {
    float w = Wk[(size_t)j * ND];
#pragma unroll
    for (int bb = 0; bb < 8; ++bb) acc[bb] += vbuf[bb][j] * w;
  }
#pragma unroll
  for (int bb = 0; bb < 8; ++bb) atomicAdd(&ctx[(b0 + bb) * ND + e], acc[bb]);
}

__global__ __launch_bounds__(256) void k_gemm_scores(const unsigned short* __restrict__ mp,
                                                     const unsigned short* __restrict__ w1mt,
                                                     const float* __restrict__ ctx,
                                                     const float* __restrict__ b1,
                                                     const float* __restrict__ w2,
                                                     float* __restrict__ scores) {
  __shared__ char lds[32768];
  char* ldsA = lds;
  char* ldsB = lds + 16384;
  const int tid = threadIdx.x;
  const int wave = tid >> 6, lane = tid & 63;
  const int bid = blockIdx.x;
  const int xcd = bid & 7, j = bid >> 3;
  const int et = j % 6;
  const int rt = xcd * 32 + j / 6;
  const int row0 = rt * 128, n0 = et * 128;
  const int b = row0 >> 9;
  const int wm = wave & 1, wn = wave >> 1;
  const int lrow = lane >> 3;
  const int qlog = (lane & 7) ^ lrow;
  const char* Abase = (const char*)mp + (size_t)(row0 + lrow) * (ND * 2) + qlog * 16;
  const char* Bbase = (const char*)w1mt + (size_t)(n0 + lrow) * (ND * 2) + qlog * 16;

  f32x4 acc[4][4];
#pragma unroll
  for (int i = 0; i < 4; ++i)
#pragma unroll
    for (int t = 0; t < 4; ++t) acc[i][t] = (f32x4){0.f, 0.f, 0.f, 0.f};

  const int q2 = lane >> 4, c = lane & 15;
  int offA0[4], offB0[4];
#pragma unroll
  for (int i = 0; i < 4; ++i) {
    int ml = wm * 64 + i * 16 + c;
    offA0[i] = ml * 128 + ((q2 ^ (ml & 7)) * 16);
    int nl = wn * 64 + i * 16 + c;
    offB0[i] = nl * 128 + ((q2 ^ (nl & 7)) * 16);
  }

  for (int kb = 0; kb < ND * 2; kb += 128) {
#pragma unroll
    for (int i = 0; i < 4; ++i) {
      int g = wave * 4 + i;
      async_copy16(Abase + (size_t)g * 8 * (ND * 2) + kb, ldsA + g * 1024);
      async_copy16(Bbase + (size_t)g * 8 * (ND * 2) + kb, ldsB + g * 1024);
    }
    __syncthreads();
#pragma unroll
    for (int kk = 0; kk < 2; ++kk) {
      const int x = kk * 64;
      bf16x8 bfrag[4];
#pragma unroll
      for (int t = 0; t < 4; ++t) bfrag[t] = *(const bf16x8*)(ldsB + (offB0[t] ^ x));
#pragma unroll
      for (int i = 0; i < 4; ++i) {
        bf16x8 afrag = *(const bf16x8*)(ldsA + (offA0[i] ^ x));
#pragma unroll
        for (int t = 0; t < 4; ++t)
          acc[i][t] = __builtin_amdgcn_mfma_f32_16x16x32_bf16(afrag, bfrag[t], acc[i][t], 0, 0, 0);
      }
    }
    __syncthreads();
  }

  float ctxv[4], w2v[4];
#pragma unroll
  for (int t = 0; t < 4; ++t) {
    int n = n0 + wn * 64 + t * 16 + c;
    ctxv[t] = ctx[b * ND + n] + b1[n];
    w2v[t] = w2[n];
  }
#pragma unroll
  for (int i = 0; i < 4; ++i) {
#pragma unroll
    for (int r = 0; r < 4; ++r) {
      float s = 0.f;
#pragma unroll
      for (int t = 0; t < 4; ++t) s += fast_tanh(acc[i][t][r] + ctxv[t]) * w2v[t];
      s += __shfl_xor(s, 1, 64);
      s += __shfl_xor(s, 2, 64);
      s += __shfl_xor(s, 4, 64);
      s += __shfl_xor(s, 8, 64);
      if (c == 0) atomicAdd(&scores[row0 + wm * 64 + i * 16 + q2 * 4 + r], s);
    }
  }
}

__global__ __launch_bounds__(192) void k_vts_sm(const unsigned short* __restrict__ mp,
                                                const float* __restrict__ scores,
                                                float* __restrict__ v_ts) {
  int sc = blockIdx.x, b = blockIdx.y, tid = threadIdx.x;
  int wid = tid >> 6, lane = tid & 63;
  __shared__ float sm[3], ss[3];
  __shared__ float al[32];
  float v[3];
#pragma unroll
  for (int k = 0; k < 3; ++k) {
    int j = tid + k * 192;
    v[k] = (j < NS) ? scores[b * NS + j] : -1e30f;
  }
  float m = fmaxf(fmaxf(v[0], v[1]), v[2]);
  for (int off = 1; off < 64; off <<= 1) m = fmaxf(m, __shfl_xor(m, off, 64));
  if (lane == 0) sm[wid] = m;
  __syncthreads();
  float M = fmaxf(fmaxf(sm[0], sm[1]), sm[2]);
  float e = 0.f;
#pragma unroll
  for (int k = 0; k < 3; ++k)
    if (tid + k * 192 < NS) e += __expf(v[k] - M);
  for (int off = 1; off < 64; off <<= 1) e += __shfl_xor(e, off, 64);
  if (lane == 0) ss[wid] = e;
  __syncthreads();
  float invS = 1.0f / (ss[0] + ss[1] + ss[2]);
  if (tid < 32) al[tid] = __expf(scores[b * NS + sc * 32 + tid] - M) * invS;
  __syncthreads();

  int d0 = tid * 4;
  float a0 = 0, a1 = 0, a2 = 0, a3 = 0;
  for (int s = 0; s < 32; ++s) {
    size_t row = (size_t)b * NS + sc * 32 + s;
    uint2 pk = *(const uint2*)(mp + row * ND + d0);
    float a = al[s];
    a0 += a * __uint_as_float(pk.x << 16);
    a1 += a * __uint_as_float(pk.x & 0xFFFF0000u);
    a2 += a * __uint_as_float(pk.y << 16);
    a3 += a * __uint_as_float(pk.y & 0xFFFF0000u);
  }
  float* p = v_ts + b * ND + d0;
  atomicAdd(p + 0, a0);
  atomicAdd(p + 1, a1);
  atomicAdd(p + 2, a2);
  atomicAdd(p + 3, a3);
}

__global__ __launch_bounds__(256) void k_final1(const float* __restrict__ v_ts,
                                                const float* __restrict__ v_s,
                                                const float* __restrict__ Wm,
                                                float* __restrict__ u) {
  int et = blockIdx.x, bt = blockIdx.y, dc = blockIdx.z, tid = threadIdx.x;
  __shared__ float vbuf[8][192];
  int b0 = bt * 8;
  for (int l = tid; l < 8 * 192; l += 256) {
    int bb = l / 192, jj = l % 192;
    int d = dc * 192 + jj;
    vbuf[bb][jj] = v_ts[(b0 + bb) * ND + d] + v_s[(b0 + bb) * ND + d];
  }
  __syncthreads();
  int e = et * 256 + tid;
  const float* Wk = Wm + (size_t)(dc * 192) * ND + e;
  float acc[8] = {0.f, 0.f, 0.f, 0.f, 0.f, 0.f, 0.f, 0.f};
#pragma unroll 4
  for (int j = 0; j < 192; ++j) {
    float w = Wk[(size_t)j * ND];
#pragma unroll
    for (int bb = 0; bb < 8; ++bb) acc[bb] += vbuf[bb][j] * w;
  }
#pragma unroll
  for (int bb = 0; bb < 8; ++bb) atomicAdd(&u[(b0 + bb) * ND + e], acc[bb]);
}

__global__ __launch_bounds__(256) void k_final2(const float* __restrict__ u,
                                                const float* __restrict__ bm,
                                                const float* __restrict__ Wd,
                                                const float* __restrict__ bd,
                                                float* __restrict__ out) {
  int b = blockIdx.x, tid = threadIdx.x;
  int wid = tid >> 6, lane = tid & 63;
  __shared__ float red[4][3];
  float p0 = 0, p1 = 0, p2 = 0;
  for (int e = tid; e < ND; e += 256) {
    float vm = fast_tanh(u[b * ND + e] + bm[e]);
    p0 += vm * Wd[e * 3 + 0];
    p1 += vm * Wd[e * 3 + 1];
    p2 += vm * Wd[e * 3 + 2];
  }
  for (int off = 1; off < 64; off <<= 1) {
    p0 += __shfl_xor(p0, off, 64);
    p1 += __shfl_xor(p1, off, 64);
    p2 += __shfl_xor(p2, off, 64);
  }
  if (lane == 0) { red[wid][0] = p0; red[wid][1] = p1; red[wid][2] = p2; }
  __syncthreads();
  if (tid == 0) {
    out[b * 3 + 0] = red[0][0] + red[1][0] + red[2][0] + red[3][0] + bd[0];
    out[b * 3 + 1] = red[0][1] + red[1][1] + red[2][1] + red[3][1] + bd[1];
    out[b * 3 + 2] = red[0][2] + red[1][2] + red[2][2] + red[3][2] + bd[2];
  }
}

extern "C" void kernel_launch(void* const* d_in, const int* in_sizes, int n_in,
                              void* d_out, int out_size, void* d_ws, size_t ws_size,
                              hipStream_t stream) {
  const float* memory = (const float*)d_in[0];
  const float* aspect = (const float*)d_in[1];
  const int* ids = (const int*)d_in[2];
  const int* tids = (const int*)d_in[3];
  const float* W1 = (const float*)d_in[4];
  const float* b1 = (const float*)d_in[5];
  const float* w2 = (const float*)d_in[6];
  const float* Wm = (const float*)d_in[7];
  const float* bm = (const float*)d_in[8];
  const float* Wd = (const float*)d_in[9];
  const float* bd = (const float*)d_in[10];
  float* out = (float*)d_out;

  char* ws = (char*)d_ws;
  float* scores = (float*)(ws + OFF_SCORES);
  float* v_s = (float*)(ws + OFF_VS);
  float* v_ts = (float*)(ws + OFF_VTS);
  float* ctx = (float*)(ws + OFF_CTX);
  float* u = (float*)(ws + OFF_U);
  float* v_a = (float*)(ws + OFF_VA);
  float* lens = (float*)(ws + OFF_LENS);
  unsigned short* w1mt = (unsigned short*)(ws + OFF_W1MT);
  unsigned short* mp = (unsigned short*)(ws + OFF_MP);

  // Size the cooperative grid from the real occupancy of k_mega.
  int nb_per_cu = 0;
  hipError_t qe = hipOccupancyMaxActiveBlocksPerMultiprocessor(&nb_per_cu, k_mega, 256, 0);
  int grid = 0;
  if (qe == hipSuccess && nb_per_cu > 0) {
    grid = nb_per_cu * 256;  // 256 CUs on MI355X
    if (grid > 1024) grid = 1024;
  }

  hipError_t err = hipErrorUnknown;
  if (grid >= 64) {
    void* args[] = {(void*)&memory, (void*)&aspect, (void*)&ids, (void*)&tids,
                    (void*)&W1,     (void*)&b1,     (void*)&w2,  (void*)&Wm,
                    (void*)&bm,     (void*)&Wd,     (void*)&bd,  (void*)&out,
                    (void*)&scores, (void*)&v_s,    (void*)&v_ts, (void*)&ctx,
                    (void*)&u,      (void*)&v_a,    (void*)&lens, (void*)&w1mt,
                    (void*)&mp,     (void*)&ws};
    err = hipLaunchCooperativeKernel((void*)k_mega, dim3(grid), dim3(256), args, 0, stream);
  }
  if (err != hipSuccess) {
    (void)hipGetLastError();  // clear sticky error, use verified multi-kernel path
    k_pre<<<864, 256, 0, stream>>>(W1, w1mt, ids, tids, aspect, v_a, lens, ws);
    k_vs_mprime<<<dim3(16, NB), 192, 0, stream>>>(memory, lens, v_s, mp);
    k_ctx<<<dim3(3, 8, 8), 256, 0, stream>>>(W1, v_a, v_s, ctx);
    k_gemm_scores<<<1536, 256, 0, stream>>>(mp, w1mt, ctx, b1, w2, scores);
    k_vts_sm<<<dim3(16, NB), 192, 0, stream>>>(mp, scores, v_ts);
    k_final1<<<dim3(3, 8, 4), 256, 0, stream>>>(v_ts, v_s, Wm, u);
    k_final2<<<NB, 256, 0, stream>>>(u, bm, Wd, bd, out);
  }
}

// Round 8
// 623.803 us; speedup vs baseline: 1.0693x; 1.0693x over previous
//
#include <hip/hip_runtime.h>
#include <hip/hip_bf16.h>
#include <hip/hip_cooperative_groups.h>

namespace cg = cooperative_groups;

// Cabasc: B=64, S=512, Ta=8, D=768
// Round 8: re-run of round-7 (infra failure, no data). Mega-kernel with
// __launch_bounds__(256,3) (170 VGPR/wave -> no P3 scratch spill), grid from
// occupancy query, coop-support attribute check, round-4 pipeline fallback.

#define NB 64
#define NS 512
#define ND 768
#define NTA 8

typedef __attribute__((ext_vector_type(8))) __bf16 bf16x8;
typedef __attribute__((ext_vector_type(4))) float f32x4;

// ---- workspace layout (bytes) ----
#define OFF_SCORES 0u           // NB*NS f32   = 131072
#define OFF_VS 131072u          // NB*ND f32
#define OFF_VTS 327680u         // NB*ND f32
#define OFF_CTX 524288u         // NB*ND f32
#define OFF_U 720896u           // NB*ND f32
#define ZERO_BYTES 917504u      // zeroed in P0
#define OFF_VA 917504u          // NB*ND f32
#define OFF_LENS 1245184u       // mlenf[64] | inv_mlen[64] | inv_alen[64]
#define OFF_W1MT 1246208u       // ND*ND bf16
#define OFF_MP 2425856u         // NB*NS*ND bf16

__device__ __forceinline__ float fast_tanh(float x) {
  x = fminf(fmaxf(x, -15.f), 15.f);
  float t = __expf(2.f * x);
  return __fdividef(t - 1.f, t + 1.f);
}

__device__ __forceinline__ unsigned bfpack2(float a, float b) {
  unsigned ua = __float_as_uint(a), ub = __float_as_uint(b);
  ua = (ua + 0x7FFFu + ((ua >> 16) & 1u)) >> 16;
  ub = (ub + 0x7FFFu + ((ub >> 16) & 1u)) >> 16;
  return ua | (ub << 16);
}

__device__ __forceinline__ unsigned short bf16b(float f) {
  unsigned u = __float_as_uint(f);
  u = (u + 0x7FFFu + ((u >> 16) & 1u)) >> 16;
  return (unsigned short)u;
}

__device__ __forceinline__ void async_copy16(const void* g, void* l) {
  __builtin_amdgcn_global_load_lds(
      (const __attribute__((address_space(1))) void*)g,
      (__attribute__((address_space(3))) void*)l, 16, 0, 0);
}

// ======================= cooperative mega-kernel ===========================
__global__ __launch_bounds__(256, 3) void k_mega(
    const float* __restrict__ memory, const float* __restrict__ aspect,
    const int* __restrict__ ids, const int* __restrict__ tids,
    const float* __restrict__ W1, const float* __restrict__ b1,
    const float* __restrict__ w2, const float* __restrict__ Wm,
    const float* __restrict__ bm, const float* __restrict__ Wd,
    const float* __restrict__ bd, float* __restrict__ out,
    float* __restrict__ scores, float* __restrict__ v_s,
    float* __restrict__ v_ts, float* __restrict__ ctx, float* __restrict__ u,
    float* __restrict__ v_a, float* __restrict__ lens,
    unsigned short* __restrict__ w1mt, unsigned short* __restrict__ mp,
    char* __restrict__ zws) {
  cg::grid_group grid = cg::this_grid();
  const int bid = blockIdx.x, tid = threadIdx.x;
  const int nblk = gridDim.x;
  __shared__ __align__(16) char smem[32768];

  // ---- P0: transpose W1_m -> bf16 [e][d] / lens + v_a / zero accumulators --
  for (int vb = bid; vb < 864; vb += nblk) {
    if (vb < 576) {
      float(*tile)[33] = (float(*)[33])smem;
      int bx = vb % 24, by = vb / 24;
      int tx = tid & 31, ty = tid >> 5;
      for (int j = 0; j < 32; j += 8)
        tile[ty + j][tx] = W1[(size_t)(by * 32 + ty + j) * ND + bx * 32 + tx];
      __syncthreads();
      for (int j = 0; j < 32; j += 8)
        w1mt[(size_t)(bx * 32 + ty + j) * ND + by * 32 + tx] = bf16b(tile[tx][ty + j]);
    } else if (vb < 640) {
      int b = vb - 576;
      int* red = (int*)smem;
      float* sh_inva = (float*)(smem + 1024);
      int cnt = 0;
      for (int j = tid; j < NS; j += 256) cnt += (ids[b * NS + j] != 0);
      red[tid] = cnt;
      __syncthreads();
      for (int s = 128; s > 0; s >>= 1) {
        if (tid < s) red[tid] += red[tid + s];
        __syncthreads();
      }
      if (tid == 0) {
        int mlen = red[0];
        int acnt = 0;
        for (int t = 0; t < NTA; ++t) acnt += (tids[b * NTA + t] != 0);
        lens[b] = (float)mlen;
        lens[64 + b] = 1.0f / (float)mlen;
        float inva = 1.0f / (float)acnt;
        lens[128 + b] = inva;
        *sh_inva = inva;
      }
      __syncthreads();
      float inva = *sh_inva;
      for (int j = tid; j < ND; j += 256) {
        float s = 0.f;
        for (int t = 0; t < NTA; ++t) s += aspect[((size_t)b * NTA + t) * ND + j];
        v_a[b * ND + j] = s * inva;
      }
    } else {
      uint4 z = {0u, 0u, 0u, 0u};
      *(uint4*)(zws + (size_t)(vb - 640) * 4096 + tid * 16) = z;
    }
    __syncthreads();  // WAR guard before smem reuse next iteration
  }
  grid.sync();

  // ---- P1: v_s (mean of memory) + mp = bf16(memory*loc) --------------------
  for (int vb = bid; vb < 1024; vb += nblk) {
    int b = vb >> 4, sc = vb & 15;
    if (tid < 192) {
      int d0 = tid * 4;
      float inv_mlen = lens[64 + b];
      float mlenf = lens[b];
      float s0 = 0, s1 = 0, s2 = 0, s3 = 0;
      for (int s = 0; s < 32; ++s) {
        int srow = sc * 32 + s;
        size_t row = (size_t)b * NS + srow;
        const float4 v = *(const float4*)(memory + row * ND + d0);
        s0 += v.x; s1 += v.y; s2 += v.z; s3 += v.w;
        float fs = (float)srow;
        float loc = (fs < mlenf) ? 1.0f - fs * inv_mlen : 1.0f;
        uint2 pk;
        pk.x = bfpack2(v.x * loc, v.y * loc);
        pk.y = bfpack2(v.z * loc, v.w * loc);
        *(uint2*)(mp + row * ND + d0) = pk;
      }
      float* p = v_s + b * ND + d0;
      atomicAdd(p + 0, s0 * inv_mlen);
      atomicAdd(p + 1, s1 * inv_mlen);
      atomicAdd(p + 2, s2 * inv_mlen);
      atomicAdd(p + 3, s3 * inv_mlen);
    }
  }
  grid.sync();

  // ---- P2: ctx += partial([v_a;v_s] @ [W1_a;W1_s]) -------------------------
  for (int vb = bid; vb < 768; vb += nblk) {
    int et = vb >> 8, r = vb & 255;
    int b = r >> 2, dc = r & 3;
    float* vbuf = (float*)smem;  // 384 f32
    for (int j = tid; j < 384; j += 256) {
      int k = dc * 384 + j;
      vbuf[j] = (k < ND) ? v_a[b * ND + k] : v_s[b * ND + (k - ND)];
    }
    __syncthreads();
    int e = et * 256 + tid;
    float acc = 0.f;
    const float* Wk = W1 + (size_t)(ND + dc * 384) * ND + e;
#pragma unroll 8
    for (int j = 0; j < 384; ++j) acc += vbuf[j] * Wk[(size_t)j * ND];
    atomicAdd(&ctx[b * ND + e], acc);
    __syncthreads();
  }
  grid.sync();

  // ---- P3: big GEMM, persistent over 1536 tiles ----------------------------
  {
    char* ldsA = smem;
    char* ldsB = smem + 16384;
    const int wave = tid >> 6, lane = tid & 63;
    const int wm = wave & 1, wn = wave >> 1;
    const int lrow = lane >> 3;
    const int qlog = (lane & 7) ^ lrow;
    const int q2 = lane >> 4, c = lane & 15;

    for (int t = bid; t < 1536; t += nblk) {
      const int xcd = t & 7, jj = t >> 3;
      const int et = jj % 6;
      const int rt = xcd * 32 + jj / 6;
      const int row0 = rt * 128, n0 = et * 128;
      const int b = row0 >> 9;

      const char* Abase = (const char*)mp + (size_t)(row0 + lrow) * (ND * 2) + qlog * 16;
      const char* Bbase = (const char*)w1mt + (size_t)(n0 + lrow) * (ND * 2) + qlog * 16;

      f32x4 acc[4][4];
#pragma unroll
      for (int i = 0; i < 4; ++i)
#pragma unroll
        for (int t2 = 0; t2 < 4; ++t2) acc[i][t2] = (f32x4){0.f, 0.f, 0.f, 0.f};

      int offA0[4], offB0[4];
#pragma unroll
      for (int i = 0; i < 4; ++i) {
        int ml = wm * 64 + i * 16 + c;
        offA0[i] = ml * 128 + ((q2 ^ (ml & 7)) * 16);
        int nl = wn * 64 + i * 16 + c;
        offB0[i] = nl * 128 + ((q2 ^ (nl & 7)) * 16);
      }

      __syncthreads();
      for (int kb = 0; kb < ND * 2; kb += 128) {
#pragma unroll
        for (int i = 0; i < 4; ++i) {
          int g = wave * 4 + i;
          async_copy16(Abase + (size_t)g * 8 * (ND * 2) + kb, ldsA + g * 1024);
          async_copy16(Bbase + (size_t)g * 8 * (ND * 2) + kb, ldsB + g * 1024);
        }
        __syncthreads();
#pragma unroll
        for (int kk = 0; kk < 2; ++kk) {
          const int x = kk * 64;
          bf16x8 bfrag[4];
#pragma unroll
          for (int t2 = 0; t2 < 4; ++t2) bfrag[t2] = *(const bf16x8*)(ldsB + (offB0[t2] ^ x));
#pragma unroll
          for (int i = 0; i < 4; ++i) {
            bf16x8 afrag = *(const bf16x8*)(ldsA + (offA0[i] ^ x));
#pragma unroll
            for (int t2 = 0; t2 < 4; ++t2)
              acc[i][t2] = __builtin_amdgcn_mfma_f32_16x16x32_bf16(afrag, bfrag[t2], acc[i][t2], 0, 0, 0);
          }
        }
        __syncthreads();
      }

      float ctxv[4], w2v[4];
#pragma unroll
      for (int t2 = 0; t2 < 4; ++t2) {
        int n = n0 + wn * 64 + t2 * 16 + c;
        ctxv[t2] = ctx[b * ND + n] + b1[n];
        w2v[t2] = w2[n];
      }
#pragma unroll
      for (int i = 0; i < 4; ++i) {
#pragma unroll
        for (int r = 0; r < 4; ++r) {
          float s = 0.f;
#pragma unroll
          for (int t2 = 0; t2 < 4; ++t2) s += fast_tanh(acc[i][t2][r] + ctxv[t2]) * w2v[t2];
          s += __shfl_xor(s, 1, 64);
          s += __shfl_xor(s, 2, 64);
          s += __shfl_xor(s, 4, 64);
          s += __shfl_xor(s, 8, 64);
          if (c == 0) atomicAdd(&scores[row0 + wm * 64 + i * 16 + q2 * 4 + r], s);
        }
      }
    }
  }
  grid.sync();

  // ---- P4: softmax + v_ts --------------------------------------------------
  for (int vb = bid; vb < 1024; vb += nblk) {
    int b = vb >> 4, sc = vb & 15;
    int wid = tid >> 6, lane = tid & 63;
    float* sm = (float*)smem;   // 4
    float* ssum = sm + 4;       // 4
    float* al = sm + 8;         // 32
    float v0 = scores[b * NS + tid];
    float v1 = scores[b * NS + 256 + tid];
    float m = fmaxf(v0, v1);
    for (int off = 1; off < 64; off <<= 1) m = fmaxf(m, __shfl_xor(m, off, 64));
    if (lane == 0) sm[wid] = m;
    __syncthreads();
    float M = fmaxf(fmaxf(sm[0], sm[1]), fmaxf(sm[2], sm[3]));
    float e = __expf(v0 - M) + __expf(v1 - M);
    for (int off = 1; off < 64; off <<= 1) e += __shfl_xor(e, off, 64);
    if (lane == 0) ssum[wid] = e;
    __syncthreads();
    float invS = 1.0f / (ssum[0] + ssum[1] + ssum[2] + ssum[3]);
    if (tid < 32) al[tid] = __expf(scores[b * NS + sc * 32 + tid] - M) * invS;
    __syncthreads();

    if (tid < 192) {
      int d0 = tid * 4;
      float a0 = 0, a1 = 0, a2 = 0, a3 = 0;
      for (int s = 0; s < 32; ++s) {
        size_t row = (size_t)b * NS + sc * 32 + s;
        uint2 pk = *(const uint2*)(mp + row * ND + d0);
        float a = al[s];
        a0 += a * __uint_as_float(pk.x << 16);
        a1 += a * __uint_as_float(pk.x & 0xFFFF0000u);
        a2 += a * __uint_as_float(pk.y << 16);
        a3 += a * __uint_as_float(pk.y & 0xFFFF0000u);
      }
      float* p = v_ts + b * ND + d0;
      atomicAdd(p + 0, a0);
      atomicAdd(p + 1, a1);
      atomicAdd(p + 2, a2);
      atomicAdd(p + 3, a3);
    }
    __syncthreads();
  }
  grid.sync();

  // ---- P5: u += partial((v_ts+v_s) @ Wm) -----------------------------------
  for (int vb = bid; vb < 768; vb += nblk) {
    int et = vb >> 8, r = vb & 255;
    int b = r >> 2, dc = r & 3;
    float* vbuf = (float*)smem;  // 192 f32
    for (int j = tid; j < 192; j += 256) {
      int d = dc * 192 + j;
      vbuf[j] = v_ts[b * ND + d] + v_s[b * ND + d];
    }
    __syncthreads();
    int e = et * 256 + tid;
    float acc = 0.f;
    const float* Wk = Wm + (size_t)(dc * 192) * ND + e;
#pragma unroll 8
    for (int j = 0; j < 192; ++j) acc += vbuf[j] * Wk[(size_t)j * ND];
    atomicAdd(&u[b * ND + e], acc);
    __syncthreads();
  }
  grid.sync();

  // ---- P6: logits = tanh(u+bm) @ Wd + bd -----------------------------------
  for (int vb = bid; vb < NB; vb += nblk) {
    int b = vb;
    int wid = tid >> 6, lane = tid & 63;
    float* red = (float*)smem;  // [4][3]
    float p0 = 0, p1 = 0, p2 = 0;
    for (int e = tid; e < ND; e += 256) {
      float vm = fast_tanh(u[b * ND + e] + bm[e]);
      p0 += vm * Wd[e * 3 + 0];
      p1 += vm * Wd[e * 3 + 1];
      p2 += vm * Wd[e * 3 + 2];
    }
    for (int off = 1; off < 64; off <<= 1) {
      p0 += __shfl_xor(p0, off, 64);
      p1 += __shfl_xor(p1, off, 64);
      p2 += __shfl_xor(p2, off, 64);
    }
    if (lane == 0) { red[wid * 3 + 0] = p0; red[wid * 3 + 1] = p1; red[wid * 3 + 2] = p2; }
    __syncthreads();
    if (tid == 0) {
      out[b * 3 + 0] = red[0] + red[3] + red[6] + red[9] + bd[0];
      out[b * 3 + 1] = red[1] + red[4] + red[7] + red[10] + bd[1];
      out[b * 3 + 2] = red[2] + red[5] + red[8] + red[11] + bd[2];
    }
    __syncthreads();
  }
}

// ======================= fallback kernels (round-4, verified) ===============
__global__ __launch_bounds__(256) void k_pre(const float* __restrict__ W1,
                                             unsigned short* __restrict__ w1mt,
                                             const int* __restrict__ ids,
                                             const int* __restrict__ tids,
                                             const float* __restrict__ aspect,
                                             float* __restrict__ v_a,
                                             float* __restrict__ lens,
                                             char* __restrict__ zws) {
  int bid = blockIdx.x, tid = threadIdx.x;
  if (bid < 576) {
    __shared__ float tile[32][33];
    int bx = bid % 24, by = bid / 24;
    int tx = tid & 31, ty = tid >> 5;
    for (int j = 0; j < 32; j += 8)
      tile[ty + j][tx] = W1[(size_t)(by * 32 + ty + j) * ND + bx * 32 + tx];
    __syncthreads();
    for (int j = 0; j < 32; j += 8)
      w1mt[(size_t)(bx * 32 + ty + j) * ND + by * 32 + tx] = bf16b(tile[tx][ty + j]);
  } else if (bid < 640) {
    int b = bid - 576;
    __shared__ int red[256];
    __shared__ float sh_inva;
    int cnt = 0;
    for (int j = tid; j < NS; j += 256) cnt += (ids[b * NS + j] != 0);
    red[tid] = cnt;
    __syncthreads();
    for (int s = 128; s > 0; s >>= 1) {
      if (tid < s) red[tid] += red[tid + s];
      __syncthreads();
    }
    if (tid == 0) {
      int mlen = red[0];
      int acnt = 0;
      for (int t = 0; t < NTA; ++t) acnt += (tids[b * NTA + t] != 0);
      lens[b] = (float)mlen;
      lens[64 + b] = 1.0f / (float)mlen;
      float inva = 1.0f / (float)acnt;
      lens[128 + b] = inva;
      sh_inva = inva;
    }
    __syncthreads();
    float inva = sh_inva;
    for (int j = tid; j < ND; j += 256) {
      float s = 0.f;
      for (int t = 0; t < NTA; ++t) s += aspect[((size_t)b * NTA + t) * ND + j];
      v_a[b * ND + j] = s * inva;
    }
  } else {
    uint4 z = {0u, 0u, 0u, 0u};
    *(uint4*)(zws + (size_t)(bid - 640) * 4096 + tid * 16) = z;
  }
}

__global__ __launch_bounds__(192) void k_vs_mprime(const float* __restrict__ memory,
                                                   const float* __restrict__ lens,
                                                   float* __restrict__ v_s,
                                                   unsigned short* __restrict__ mp) {
  int sc = blockIdx.x, b = blockIdx.y, tid = threadIdx.x;
  int d0 = tid * 4;
  float inv_mlen = lens[64 + b];
  float mlenf = lens[b];
  float s0 = 0, s1 = 0, s2 = 0, s3 = 0;
  for (int s = 0; s < 32; ++s) {
    int srow = sc * 32 + s;
    size_t row = (size_t)b * NS + srow;
    const float4 v = *(const float4*)(memory + row * ND + d0);
    s0 += v.x; s1 += v.y; s2 += v.z; s3 += v.w;
    float fs = (float)srow;
    float loc = (fs < mlenf) ? 1.0f - fs * inv_mlen : 1.0f;
    uint2 pk;
    pk.x = bfpack2(v.x * loc, v.y * loc);
    pk.y = bfpack2(v.z * loc, v.w * loc);
    *(uint2*)(mp + row * ND + d0) = pk;
  }
  float* p = v_s + b * ND + d0;
  atomicAdd(p + 0, s0 * inv_mlen);
  atomicAdd(p + 1, s1 * inv_mlen);
  atomicAdd(p + 2, s2 * inv_mlen);
  atomicAdd(p + 3, s3 * inv_mlen);
}

__global__ __launch_bounds__(256) void k_ctx(const float* __restrict__ W1,
                                             const float* __restrict__ v_a,
                                             const float* __restrict__ v_s,
                                             float* __restrict__ ctx) {
  int et = blockIdx.x, bt = blockIdx.y, dc = blockIdx.z, tid = threadIdx.x;
  __shared__ float vbuf[8][192];
  int b0 = bt * 8;
  for (int l = tid; l < 8 * 192; l += 256) {
    int bb = l / 192, jj = l % 192;
    int k = dc * 192 + jj;
    vbuf[bb][jj] = (k < ND) ? v_a[(b0 + bb) * ND + k] : v_s[(b0 + bb) * ND + (k - ND)];
  }
  __syncthreads();
  int e = et * 256 + tid;
  const float* Wk = W1 + (size_t)(ND + dc * 192) * ND + e;
  float acc[8] = {0.f, 0.f, 0.f, 0.f, 0.f, 0.f, 0.f, 0.f};
#pragma unroll 4
  for (int j = 0; j < 192; ++j) {
    float w = Wk[(size_t)j * ND];
#pragma unroll
    for (int bb = 0; bb < 8; ++bb) acc[bb] += vbuf[bb][j] * w;
  }
#pragma unroll
  for (int bb = 0; bb < 8; ++bb) atomicAdd(&ctx[(b0 + bb) * ND + e], acc[bb]);
}

__global__ __launch_bounds__(256) void k_gemm_scores(const unsigned short* __restrict__ mp,
                                                     const unsigned short* __restrict__ w1mt,
                                                     const float* __restrict__ ctx,
                                                     const float* __restrict__ b1,
                                                     const float* __restrict__ w2,
                                                     float* __restrict__ scores) {
  __shared__ char lds[32768];
  char* ldsA = lds;
  char* ldsB = lds + 16384;
  const int tid = threadIdx.x;
  const int wave = tid >> 6, lane = tid & 63;
  const int bid = blockIdx.x;
  const int xcd = bid & 7, j = bid >> 3;
  const int et = j % 6;
  const int rt = xcd * 32 + j / 6;
  const int row0 = rt * 128, n0 = et * 128;
  const int b = row0 >> 9;
  const int wm = wave & 1, wn = wave >> 1;
  const int lrow = lane >> 3;
  const int qlog = (lane & 7) ^ lrow;
  const char* Abase = (const char*)mp + (size_t)(row0 + lrow) * (ND * 2) + qlog * 16;
  const char* Bbase = (const char*)w1mt + (size_t)(n0 + lrow) * (ND * 2) + qlog * 16;

  f32x4 acc[4][4];
#pragma unroll
  for (int i = 0; i < 4; ++i)
#pragma unroll
    for (int t = 0; t < 4; ++t) acc[i][t] = (f32x4){0.f, 0.f, 0.f, 0.f};

  const int q2 = lane >> 4, c = lane & 15;
  int offA0[4], offB0[4];
#pragma unroll
  for (int i = 0; i < 4; ++i) {
    int ml = wm * 64 + i * 16 + c;
    offA0[i] = ml * 128 + ((q2 ^ (ml & 7)) * 16);
    int nl = wn * 64 + i * 16 + c;
    offB0[i] = nl * 128 + ((q2 ^ (nl & 7)) * 16);
  }

  for (int kb = 0; kb < ND * 2; kb += 128) {
#pragma unroll
    for (int i = 0; i < 4; ++i) {
      int g = wave * 4 + i;
      async_copy16(Abase + (size_t)g * 8 * (ND * 2) + kb, ldsA + g * 1024);
      async_copy16(Bbase + (size_t)g * 8 * (ND * 2) + kb, ldsB + g * 1024);
    }
    __syncthreads();
#pragma unroll
    for (int kk = 0; kk < 2; ++kk) {
      const int x = kk * 64;
      bf16x8 bfrag[4];
#pragma unroll
      for (int t = 0; t < 4; ++t) bfrag[t] = *(const bf16x8*)(ldsB + (offB0[t] ^ x));
#pragma unroll
      for (int i = 0; i < 4; ++i) {
        bf16x8 afrag = *(const bf16x8*)(ldsA + (offA0[i] ^ x));
#pragma unroll
        for (int t = 0; t < 4; ++t)
          acc[i][t] = __builtin_amdgcn_mfma_f32_16x16x32_bf16(afrag, bfrag[t], acc[i][t], 0, 0, 0);
      }
    }
    __syncthreads();
  }

  float ctxv[4], w2v[4];
#pragma unroll
  for (int t = 0; t < 4; ++t) {
    int n = n0 + wn * 64 + t * 16 + c;
    ctxv[t] = ctx[b * ND + n] + b1[n];
    w2v[t] = w2[n];
  }
#pragma unroll
  for (int i = 0; i < 4; ++i) {
#pragma unroll
    for (int r = 0; r < 4; ++r) {
      float s = 0.f;
#pragma unroll
      for (int t = 0; t < 4; ++t) s += fast_tanh(acc[i][t][r] + ctxv[t]) * w2v[t];
      s += __shfl_xor(s, 1, 64);
      s += __shfl_xor(s, 2, 64);
      s += __shfl_xor(s, 4, 64);
      s += __shfl_xor(s, 8, 64);
      if (c == 0) atomicAdd(&scores[row0 + wm * 64 + i * 16 + q2 * 4 + r], s);
    }
  }
}

__global__ __launch_bounds__(192) void k_vts_sm(const unsigned short* __restrict__ mp,
                                                const float* __restrict__ scores,
                                                float* __restrict__ v_ts) {
  int sc = blockIdx.x, b = blockIdx.y, tid = threadIdx.x;
  int wid = tid >> 6, lane = tid & 63;
  __shared__ float sm[3], ss[3];
  __shared__ float al[32];
  float v[3];
#pragma unroll
  for (int k = 0; k < 3; ++k) {
    int j = tid + k * 192;
    v[k] = (j < NS) ? scores[b * NS + j] : -1e30f;
  }
  float m = fmaxf(fmaxf(v[0], v[1]), v[2]);
  for (int off = 1; off < 64; off <<= 1) m = fmaxf(m, __shfl_xor(m, off, 64));
  if (lane == 0) sm[wid] = m;
  __syncthreads();
  float M = fmaxf(fmaxf(sm[0], sm[1]), sm[2]);
  float e = 0.f;
#pragma unroll
  for (int k = 0; k < 3; ++k)
    if (tid + k * 192 < NS) e += __expf(v[k] - M);
  for (int off = 1; off < 64; off <<= 1) e += __shfl_xor(e, off, 64);
  if (lane == 0) ss[wid] = e;
  __syncthreads();
  float invS = 1.0f / (ss[0] + ss[1] + ss[2]);
  if (tid < 32) al[tid] = __expf(scores[b * NS + sc * 32 + tid] - M) * invS;
  __syncthreads();

  int d0 = tid * 4;
  float a0 = 0, a1 = 0, a2 = 0, a3 = 0;
  for (int s = 0; s < 32; ++s) {
    size_t row = (size_t)b * NS + sc * 32 + s;
    uint2 pk = *(const uint2*)(mp + row * ND + d0);
    float a = al[s];
    a0 += a * __uint_as_float(pk.x << 16);
    a1 += a * __uint_as_float(pk.x & 0xFFFF0000u);
    a2 += a * __uint_as_float(pk.y << 16);
    a3 += a * __uint_as_float(pk.y & 0xFFFF0000u);
  }
  float* p = v_ts + b * ND + d0;
  atomicAdd(p + 0, a0);
  atomicAdd(p + 1, a1);
  atomicAdd(p + 2, a2);
  atomicAdd(p + 3, a3);
}

__global__ __launch_bounds__(256) void k_final1(const float* __restrict__ v_ts,
                                                const float* __restrict__ v_s,
                                                const float* __restrict__ Wm,
                                                float* __restrict__ u) {
  int et = blockIdx.x, bt = blockIdx.y, dc = blockIdx.z, tid = threadIdx.x;
  __shared__ float vbuf[8][192];
  int b0 = bt * 8;
  for (int l = tid; l < 8 * 192; l += 256) {
    int bb = l / 192, jj = l % 192;
    int d = dc * 192 + jj;
    vbuf[bb][jj] = v_ts[(b0 + bb) * ND + d] + v_s[(b0 + bb) * ND + d];
  }
  __syncthreads();
  int e = et * 256 + tid;
  const float* Wk = Wm + (size_t)(dc * 192) * ND + e;
  float acc[8] = {0.f, 0.f, 0.f, 0.f, 0.f, 0.f, 0.f, 0.f};
#pragma unroll 4
  for (int j = 0; j < 192; ++j) {
    float w = Wk[(size_t)j * ND];
#pragma unroll
    for (int bb = 0; bb < 8; ++bb) acc[bb] += vbuf[bb][j] * w;
  }
#pragma unroll
  for (int bb = 0; bb < 8; ++bb) atomicAdd(&u[(b0 + bb) * ND + e], acc[bb]);
}

__global__ __launch_bounds__(256) void k_final2(const float* __restrict__ u,
                                                const float* __restrict__ bm,
                                                const float* __restrict__ Wd,
                                                const float* __restrict__ bd,
                                                float* __restrict__ out) {
  int b = blockIdx.x, tid = threadIdx.x;
  int wid = tid >> 6, lane = tid & 63;
  __shared__ float red[4][3];
  float p0 = 0, p1 = 0, p2 = 0;
  for (int e = tid; e < ND; e += 256) {
    float vm = fast_tanh(u[b * ND + e] + bm[e]);
    p0 += vm * Wd[e * 3 + 0];
    p1 += vm * Wd[e * 3 + 1];
    p2 += vm * Wd[e * 3 + 2];
  }
  for (int off = 1; off < 64; off <<= 1) {
    p0 += __shfl_xor(p0, off, 64);
    p1 += __shfl_xor(p1, off, 64);
    p2 += __shfl_xor(p2, off, 64);
  }
  if (lane == 0) { red[wid][0] = p0; red[wid][1] = p1; red[wid][2] = p2; }
  __syncthreads();
  if (tid == 0) {
    out[b * 3 + 0] = red[0][0] + red[1][0] + red[2][0] + red[3][0] + bd[0];
    out[b * 3 + 1] = red[0][1] + red[1][1] + red[2][1] + red[3][1] + bd[1];
    out[b * 3 + 2] = red[0][2] + red[1][2] + red[2][2] + red[3][2] + bd[2];
  }
}

extern "C" void kernel_launch(void* const* d_in, const int* in_sizes, int n_in,
                              void* d_out, int out_size, void* d_ws, size_t ws_size,
                              hipStream_t stream) {
  const float* memory = (const float*)d_in[0];
  const float* aspect = (const float*)d_in[1];
  const int* ids = (const int*)d_in[2];
  const int* tids = (const int*)d_in[3];
  const float* W1 = (const float*)d_in[4];
  const float* b1 = (const float*)d_in[5];
  const float* w2 = (const float*)d_in[6];
  const float* Wm = (const float*)d_in[7];
  const float* bm = (const float*)d_in[8];
  const float* Wd = (const float*)d_in[9];
  const float* bd = (const float*)d_in[10];
  float* out = (float*)d_out;

  char* ws = (char*)d_ws;
  float* scores = (float*)(ws + OFF_SCORES);
  float* v_s = (float*)(ws + OFF_VS);
  float* v_ts = (float*)(ws + OFF_VTS);
  float* ctx = (float*)(ws + OFF_CTX);
  float* u = (float*)(ws + OFF_U);
  float* v_a = (float*)(ws + OFF_VA);
  float* lens = (float*)(ws + OFF_LENS);
  unsigned short* w1mt = (unsigned short*)(ws + OFF_W1MT);
  unsigned short* mp = (unsigned short*)(ws + OFF_MP);

  // Coop-launch support + occupancy-sized grid.
  int coop = 0, dev = 0;
  hipGetDevice(&dev);
  hipDeviceGetAttribute(&coop, hipDeviceAttributeCooperativeLaunch, dev);
  int nb_per_cu = 0;
  hipError_t qe = hipOccupancyMaxActiveBlocksPerMultiprocessor(&nb_per_cu, k_mega, 256, 0);
  int grid = 0;
  if (coop && qe == hipSuccess && nb_per_cu > 0) {
    grid = nb_per_cu * 256;  // 256 CUs on MI355X
    if (grid > 1024) grid = 1024;
  }

  hipError_t err = hipErrorUnknown;
  if (grid >= 64) {
    void* args[] = {(void*)&memory, (void*)&aspect, (void*)&ids, (void*)&tids,
                    (void*)&W1,     (void*)&b1,     (void*)&w2,  (void*)&Wm,
                    (void*)&bm,     (void*)&Wd,     (void*)&bd,  (void*)&out,
                    (void*)&scores, (void*)&v_s,    (void*)&v_ts, (void*)&ctx,
                    (void*)&u,      (void*)&v_a,    (void*)&lens, (void*)&w1mt,
                    (void*)&mp,     (void*)&ws};
    err = hipLaunchCooperativeKernel((void*)k_mega, dim3(grid), dim3(256), args, 0, stream);
  }
  if (err != hipSuccess) {
    (void)hipGetLastError();  // clear sticky error, use verified multi-kernel path
    k_pre<<<864, 256, 0, stream>>>(W1, w1mt, ids, tids, aspect, v_a, lens, ws);
    k_vs_mprime<<<dim3(16, NB), 192, 0, stream>>>(memory, lens, v_s, mp);
    k_ctx<<<dim3(3, 8, 8), 256, 0, stream>>>(W1, v_a, v_s, ctx);
    k_gemm_scores<<<1536, 256, 0, stream>>>(mp, w1mt, ctx, b1, w2, scores);
    k_vts_sm<<<dim3(16, NB), 192, 0, stream>>>(mp, scores, v_ts);
    k_final1<<<dim3(3, 8, 4), 256, 0, stream>>>(v_ts, v_s, Wm, u);
    k_final2<<<NB, 256, 0, stream>>>(u, bm, Wd, bd, out);
  }
}